// Round 13
// baseline (329.408 us; speedup 1.0000x reference)
//
#include <hip/hip_runtime.h>

constexpr int N_NODES = 50000;
constexpr int N_EDGES = 800000;
constexpr int F_IN  = 512;
constexpr int F_H1  = 256;
constexpr int F_H2  = 128;

typedef short  short8  __attribute__((ext_vector_type(8)));
typedef float  f32x4   __attribute__((ext_vector_type(4)));
typedef unsigned short us4 __attribute__((ext_vector_type(4)));

__device__ __forceinline__ unsigned short bf16_rn(float f) {
  unsigned int u = __float_as_uint(f);
  return (unsigned short)((u + 0x7FFFu + ((u >> 16) & 1u)) >> 16);
}
__device__ __forceinline__ float bf16_tof(unsigned short h) {
  return __uint_as_float(((unsigned int)h) << 16);
}

// ---------------- prep: weight transpose+split AND degree count (one launch) -
__global__ __launch_bounds__(256) void k_prep(const float* __restrict__ W1,
                                              unsigned short* __restrict__ W1h,
                                              unsigned short* __restrict__ W1l,
                                              const float* __restrict__ W2,
                                              unsigned short* __restrict__ W2h,
                                              unsigned short* __restrict__ W2l,
                                              const int* __restrict__ dst,
                                              int* __restrict__ cnt) {
  constexpr int T1 = F_IN * F_H1;
  constexpr int T2 = F_H1 * F_H2;
  constexpr int TW = T1 + T2;
  int id = blockIdx.x * 256 + threadIdx.x;
  if (id < T1) {
    int n = id / F_IN, k = id - n * F_IN;
    float f = W1[(size_t)k * F_H1 + n];
    unsigned short h = bf16_rn(f);
    W1h[id] = h;
    W1l[id] = bf16_rn(f - bf16_tof(h));
  } else if (id < TW) {
    int id2 = id - T1;
    int n = id2 / F_H1, k = id2 - n * F_H1;
    float f = W2[(size_t)k * F_H2 + n];
    unsigned short h = bf16_rn(f);
    W2h[id2] = h;
    W2l[id2] = bf16_rn(f - bf16_tof(h));
  } else if (id - TW < N_EDGES) {
    atomicAdd(&cnt[dst[id - TW]], 1);
  }
}

// Single block, 1024 threads, 4 elems/thread, shuffle-based scan.
__global__ __launch_bounds__(1024) void k_scan(const int* __restrict__ cnt,
                                               int* __restrict__ rowstart,
                                               int* __restrict__ cursor,
                                               float* __restrict__ dinv, int n) {
  __shared__ int wsum[16];
  __shared__ int carry_s;
  const int t = threadIdx.x;
  const int wid = t >> 6, lane = t & 63;
  if (t == 0) { carry_s = 0; rowstart[0] = 0; }
  __syncthreads();
  for (int base = 0; base < n; base += 4096) {
    const int i0 = base + t * 4;
    int v[4];
    if (i0 + 4 <= n) {
      const int4 v4 = *(const int4*)&cnt[i0];
      v[0] = v4.x; v[1] = v4.y; v[2] = v4.z; v[3] = v4.w;
    } else {
#pragma unroll
      for (int j = 0; j < 4; ++j) v[j] = (i0 + j < n) ? cnt[i0 + j] : 0;
    }
#pragma unroll
    for (int j = 0; j < 4; ++j)
      if (i0 + j < n) dinv[i0 + j] = rsqrtf((float)v[j] + 1.0f);
    const int tsum = v[0] + v[1] + v[2] + v[3];
    int x = tsum;
#pragma unroll
    for (int off = 1; off < 64; off <<= 1) {
      int y = __shfl_up(x, off);
      if (lane >= off) x += y;
    }
    if (lane == 63) wsum[wid] = x;
    __syncthreads();
    if (wid == 0) {
      int s = (lane < 16) ? wsum[lane] : 0;
#pragma unroll
      for (int off = 1; off < 16; off <<= 1) {
        int y = __shfl_up(s, off);
        if (lane >= off) s += y;
      }
      if (lane < 16) wsum[lane] = s;
    }
    __syncthreads();
    const int carry = carry_s;
    const int woff = (wid == 0) ? 0 : wsum[wid - 1];
    int run = carry + woff + x - tsum;  // exclusive prefix of first elem
#pragma unroll
    for (int j = 0; j < 4; ++j) {
      if (i0 + j < n) {
        cursor[i0 + j] = run;
        run += v[j];
        rowstart[i0 + j + 1] = run;
      }
    }
    __syncthreads();
    if (t == 1023) carry_s = carry + woff + x;
    __syncthreads();
  }
}

// Fill packed CSR: (src, coef) with coef = dinv[src]*dinv[dst].
__global__ __launch_bounds__(256) void k_fill(const int* __restrict__ src,
                                              const int* __restrict__ dst,
                                              int* __restrict__ cursor,
                                              const float* __restrict__ dinv,
                                              int2* __restrict__ csr, int e) {
  int i = blockIdx.x * 256 + threadIdx.x;
  if (i < e) {
    const int s = src[i], d = dst[i];
    int slot = atomicAdd(&cursor[d], 1);
    csr[slot] = make_int2(s, __float_as_int(dinv[s] * dinv[d]));
  }
}

// ---------------- 2-term split-bf16 MFMA GEMM (R10/R12 structure) ------------
// C = A @ B, A ~ bf16-hi (1 plane), B = Bh+Bl pre-transposed Bt[N][K].
// C written as two bf16 planes. 128x128 tile, BK=64, XOR-swizzled LDS,
// 48KB LDS -> 3 blocks/CU (VGPR 60). 512 threads = 8 waves (2x4),
// wave = 64x32 out via 4x2 frags of 16x16x32. T14 reg-prefetch.
template <bool A_IS_F32>
__global__ __launch_bounds__(512, 2) void k_mm(const float* __restrict__ Af,
                                               const unsigned short* __restrict__ Ah,
                                               const unsigned short* __restrict__ Bth,
                                               const unsigned short* __restrict__ Btl,
                                               unsigned short* __restrict__ Chh,
                                               unsigned short* __restrict__ Cll,
                                               int M, int N, int K) {
  __shared__ unsigned short Ah_s[128 * 64];
  __shared__ unsigned short Bh_s[128 * 64];
  __shared__ unsigned short Bl_s[128 * 64];
  const int tid = threadIdx.x;
  const int wid = tid >> 6, lane = tid & 63;
  const int wm = wid >> 2, wn = wid & 3;
  const int lr = lane & 15, lg = lane >> 4;
  const int col0 = blockIdx.x * 128, row0 = blockIdx.y * 128;

  f32x4 acc[4][2] = {};

  float4 af0[2], af1[2];
  short8 ahr[2];
  short8 bhr[2], blr[2];

  const int r_base = tid >> 3, g_ld = tid & 7;

  auto load_tile = [&](int k0) {
#pragma unroll
    for (int c = 0; c < 2; ++c) {
      const int r = c * 64 + r_base;
      const int gr = row0 + r;
      if (A_IS_F32) {
        af0[c] = make_float4(0.f, 0.f, 0.f, 0.f);
        af1[c] = af0[c];
        if (gr < M) {
          const float* ap = Af + (size_t)gr * K + k0 + g_ld * 8;
          af0[c] = *(const float4*)ap;
          af1[c] = *(const float4*)(ap + 4);
        }
      } else {
        ahr[c] = short8{};
        if (gr < M)
          ahr[c] = *(const short8*)&Ah[(size_t)gr * K + k0 + g_ld * 8];
      }
      const int gcol = col0 + r;
      bhr[c] = *(const short8*)&Bth[(size_t)gcol * K + k0 + g_ld * 8];
      blr[c] = *(const short8*)&Btl[(size_t)gcol * K + k0 + g_ld * 8];
    }
  };

  auto store_tile = [&]() {
#pragma unroll
    for (int c = 0; c < 2; ++c) {
      const int r = c * 64 + r_base;
      const int gs = g_ld ^ (r & 7);
      const int doff = r * 64 + gs * 8;
      if (A_IS_F32) {
        const float fv[8] = {af0[c].x, af0[c].y, af0[c].z, af0[c].w,
                             af1[c].x, af1[c].y, af1[c].z, af1[c].w};
        short8 hv;
#pragma unroll
        for (int j = 0; j < 8; ++j) hv[j] = (short)bf16_rn(fv[j]);
        *(short8*)&Ah_s[doff] = hv;
      } else {
        *(short8*)&Ah_s[doff] = ahr[c];
      }
      *(short8*)&Bh_s[doff] = bhr[c];
      *(short8*)&Bl_s[doff] = blr[c];
    }
  };

  const int nsteps = K >> 6;
  load_tile(0);
  for (int s = 0; s < nsteps; ++s) {
    store_tile();
    __syncthreads();
    if (s + 1 < nsteps) load_tile((s + 1) << 6);
#pragma unroll
    for (int kk = 0; kk < 2; ++kk) {
      short8 ah[4], bh[2], bl[2];
#pragma unroll
      for (int m = 0; m < 4; ++m) {
        const int r = wm * 64 + m * 16 + lr;
        const int g = kk * 4 + lg;
        ah[m] = *(const short8*)&Ah_s[r * 64 + (g ^ (r & 7)) * 8];
      }
#pragma unroll
      for (int n = 0; n < 2; ++n) {
        const int r = wn * 32 + n * 16 + lr;
        const int g = kk * 4 + lg;
        const int off = r * 64 + (g ^ (r & 7)) * 8;
        bh[n] = *(const short8*)&Bh_s[off];
        bl[n] = *(const short8*)&Bl_s[off];
      }
#pragma unroll
      for (int m = 0; m < 4; ++m)
#pragma unroll
        for (int n = 0; n < 2; ++n)
          acc[m][n] = __builtin_amdgcn_mfma_f32_16x16x32_bf16(ah[m], bh[n],
                                                              acc[m][n], 0, 0, 0);
#pragma unroll
      for (int m = 0; m < 4; ++m)
#pragma unroll
        for (int n = 0; n < 2; ++n)
          acc[m][n] = __builtin_amdgcn_mfma_f32_16x16x32_bf16(ah[m], bl[n],
                                                              acc[m][n], 0, 0, 0);
    }
    __syncthreads();
  }
#pragma unroll
  for (int m = 0; m < 4; ++m) {
#pragma unroll
    for (int j = 0; j < 4; ++j) {
      const int row = row0 + wm * 64 + m * 16 + (lane >> 4) * 4 + j;
      if (row < M) {
        const size_t base = (size_t)row * N + col0 + wn * 32 + lr;
#pragma unroll
        for (int n = 0; n < 2; ++n) {
          const float v = acc[m][n][j];
          const unsigned short hv = bf16_rn(v);
          Chh[base + n * 16] = hv;
          Cll[base + n * 16] = bf16_rn(v - bf16_tof(hv));
        }
      }
    }
  }
}

// ---------------- FUSED: agg over h1 + epilogue + (z1 @ W2) -> h2 planes -----
// Block = 256 threads = 4 waves, 16 nodes (4 per wave). Phase 1: per-node
// gather from h1-hi (uint2/lane), f32 self-term from h1 hi+lo, +bias, leaky;
// z1 row -> bf16-hi into 8KB XOR-swizzled LDS. One barrier. Phase 2: each
// wave computes h2[16 nodes][its 32 cols] = z1s @ W2(hi+lo), B-frags read
// straight from global (L2-broadcast, 0.5MB), writes h2 bf16 hi/lo planes.
// Numerics identical to the unfused z1h path (mm2 consumed z1-hi before).
__global__ __launch_bounds__(256) void k_aggmm(
    const unsigned short* __restrict__ hh, const unsigned short* __restrict__ hl,
    const int* __restrict__ rowstart, const int2* __restrict__ csr,
    const float* __restrict__ dinv, const float* __restrict__ bias,
    const unsigned short* __restrict__ W2h, const unsigned short* __restrict__ W2l,
    unsigned short* __restrict__ h2h, unsigned short* __restrict__ h2l, int n) {
  __shared__ unsigned short z1s[16 * 256];  // 8 KB, 16B-granule XOR swizzle
  const int tid = threadIdx.x;
  const int w = tid >> 6, lane = tid & 63;
  const int nb = blockIdx.x * 16;

  // ---- phase 1: gather 4 nodes per wave ----
  for (int i = 0; i < 4; ++i) {
    const int node = nb + w * 4 + i;
    const float dn = dinv[node];
    const int e0 = rowstart[node];
    const int cnt = rowstart[node + 1] - e0;
    const int2* cp = csr + e0;
    float a0 = 0.f, a1 = 0.f, a2 = 0.f, a3 = 0.f;
    int e = 0;
    for (; e + 4 <= cnt; e += 4) {
      const int2 p0 = cp[e], p1 = cp[e + 1], p2 = cp[e + 2], p3 = cp[e + 3];
      const uint2 u0 = *(const uint2*)(hh + (size_t)p0.x * F_H1 + lane * 4);
      const uint2 u1 = *(const uint2*)(hh + (size_t)p1.x * F_H1 + lane * 4);
      const uint2 u2 = *(const uint2*)(hh + (size_t)p2.x * F_H1 + lane * 4);
      const uint2 u3 = *(const uint2*)(hh + (size_t)p3.x * F_H1 + lane * 4);
      const float c0 = __int_as_float(p0.y), c1 = __int_as_float(p1.y);
      const float c2 = __int_as_float(p2.y), c3 = __int_as_float(p3.y);
      a0 += c0 * __uint_as_float(u0.x << 16) + c1 * __uint_as_float(u1.x << 16) +
            c2 * __uint_as_float(u2.x << 16) + c3 * __uint_as_float(u3.x << 16);
      a1 += c0 * __uint_as_float(u0.x & 0xffff0000u) +
            c1 * __uint_as_float(u1.x & 0xffff0000u) +
            c2 * __uint_as_float(u2.x & 0xffff0000u) +
            c3 * __uint_as_float(u3.x & 0xffff0000u);
      a2 += c0 * __uint_as_float(u0.y << 16) + c1 * __uint_as_float(u1.y << 16) +
            c2 * __uint_as_float(u2.y << 16) + c3 * __uint_as_float(u3.y << 16);
      a3 += c0 * __uint_as_float(u0.y & 0xffff0000u) +
            c1 * __uint_as_float(u1.y & 0xffff0000u) +
            c2 * __uint_as_float(u2.y & 0xffff0000u) +
            c3 * __uint_as_float(u3.y & 0xffff0000u);
    }
    for (; e < cnt; ++e) {
      const int2 pp = cp[e];
      const float c = __int_as_float(pp.y);
      const uint2 u = *(const uint2*)(hh + (size_t)pp.x * F_H1 + lane * 4);
      a0 += c * __uint_as_float(u.x << 16);
      a1 += c * __uint_as_float(u.x & 0xffff0000u);
      a2 += c * __uint_as_float(u.y << 16);
      a3 += c * __uint_as_float(u.y & 0xffff0000u);
    }
    const float sc = dn * dn;
    const unsigned short* shp = hh + (size_t)node * F_H1 + lane * 4;
    const unsigned short* slp = hl + (size_t)node * F_H1 + lane * 4;
    const float* bp = bias + lane * 4;
    float r[4] = {a0, a1, a2, a3};
#pragma unroll
    for (int j = 0; j < 4; ++j) {
      const float hself = bf16_tof(shp[j]) + bf16_tof(slp[j]);
      float t = r[j] + sc * hself + bp[j];
      r[j] = fmaxf(t, 0.2f * t);
    }
    // z1 row (bf16-hi) -> LDS, swizzled: elem c lives in 16B granule c/8,
    // granule index XORed with row&7. Lane covers cols lane*4..+3.
    const int row = w * 4 + i;
    const int gi = (lane >> 1) ^ (row & 7);
    unsigned short* dp = &z1s[row * 256 + gi * 8 + (lane & 1) * 4];
    *(us4*)dp = us4{bf16_rn(r[0]), bf16_rn(r[1]), bf16_rn(r[2]), bf16_rn(r[3])};
  }
  __syncthreads();

  // ---- phase 2: h2[16][128] = z1s @ W2 (2-term weight split) ----
  const int lr = lane & 15, lg = lane >> 4;
  f32x4 acc[2] = {{0.f, 0.f, 0.f, 0.f}, {0.f, 0.f, 0.f, 0.f}};
  const int col0 = w * 32;
#pragma unroll
  for (int kk = 0; kk < 8; ++kk) {
    const int gi = kk * 4 + lg;  // 16B granule within row (0..31)
    const short8 a = *(const short8*)&z1s[lr * 256 + (gi ^ (lr & 7)) * 8];
#pragma unroll
    for (int nn = 0; nn < 2; ++nn) {
      const int col = col0 + nn * 16 + lr;
      const short8 bh = *(const short8*)&W2h[(size_t)col * F_H1 + kk * 32 + lg * 8];
      const short8 bl = *(const short8*)&W2l[(size_t)col * F_H1 + kk * 32 + lg * 8];
      acc[nn] = __builtin_amdgcn_mfma_f32_16x16x32_bf16(a, bh, acc[nn], 0, 0, 0);
      acc[nn] = __builtin_amdgcn_mfma_f32_16x16x32_bf16(a, bl, acc[nn], 0, 0, 0);
    }
  }
#pragma unroll
  for (int nn = 0; nn < 2; ++nn) {
#pragma unroll
    for (int j = 0; j < 4; ++j) {
      const int node = nb + (lane >> 4) * 4 + j;
      const int col = col0 + nn * 16 + (lane & 15);
      const float v = acc[nn][j];
      const unsigned short hv = bf16_rn(v);
      h2h[(size_t)node * F_H2 + col] = hv;
      h2l[(size_t)node * F_H2 + col] = bf16_rn(v - bf16_tof(hv));
    }
  }
}

// ---------------- final gather aggregation + epilogue (layer 2) --------------
__global__ __launch_bounds__(256) void k_agg2(const unsigned short* __restrict__ hh,
                                              const unsigned short* __restrict__ hl,
                                              const int* __restrict__ rowstart,
                                              const int2* __restrict__ csr,
                                              const float* __restrict__ dinv,
                                              const float* __restrict__ bias,
                                              float* __restrict__ outp, int n) {
  constexpr int F = F_H2;
  const int node = (blockIdx.x * 256 + threadIdx.x) >> 6;
  const int lane = threadIdx.x & 63;
  if (node >= n) return;
  const float dn = dinv[node];
  const int e0 = rowstart[node];
  const int cnt = rowstart[node + 1] - e0;
  const int2* cp = csr + e0;
  float a0 = 0.f, a1 = 0.f;
  int i = 0;
  for (; i + 4 <= cnt; i += 4) {
    const int2 p0 = cp[i], p1 = cp[i + 1], p2 = cp[i + 2], p3 = cp[i + 3];
    const unsigned int u0 = *(const unsigned int*)(hh + (size_t)p0.x * F + lane * 2);
    const unsigned int u1 = *(const unsigned int*)(hh + (size_t)p1.x * F + lane * 2);
    const unsigned int u2 = *(const unsigned int*)(hh + (size_t)p2.x * F + lane * 2);
    const unsigned int u3 = *(const unsigned int*)(hh + (size_t)p3.x * F + lane * 2);
    const float c0 = __int_as_float(p0.y), c1 = __int_as_float(p1.y);
    const float c2 = __int_as_float(p2.y), c3 = __int_as_float(p3.y);
    a0 += c0 * __uint_as_float(u0 << 16) + c1 * __uint_as_float(u1 << 16) +
          c2 * __uint_as_float(u2 << 16) + c3 * __uint_as_float(u3 << 16);
    a1 += c0 * __uint_as_float(u0 & 0xffff0000u) +
          c1 * __uint_as_float(u1 & 0xffff0000u) +
          c2 * __uint_as_float(u2 & 0xffff0000u) +
          c3 * __uint_as_float(u3 & 0xffff0000u);
  }
  for (; i < cnt; ++i) {
    const int2 pp = cp[i];
    const float c = __int_as_float(pp.y);
    const unsigned int u = *(const unsigned int*)(hh + (size_t)pp.x * F + lane * 2);
    a0 += c * __uint_as_float(u << 16);
    a1 += c * __uint_as_float(u & 0xffff0000u);
  }
  const float sc = dn * dn;
  const unsigned short* shp = hh + (size_t)node * F + lane * 2;
  const unsigned short* slp = hl + (size_t)node * F + lane * 2;
  const float* bp = bias + lane * 2;
  const float h0 = bf16_tof(shp[0]) + bf16_tof(slp[0]);
  const float h1v = bf16_tof(shp[1]) + bf16_tof(slp[1]);
  float t0 = a0 + sc * h0 + bp[0];
  float t1 = a1 + sc * h1v + bp[1];
  t0 = fmaxf(t0, 0.2f * t0);
  t1 = fmaxf(t1, 0.2f * t1);
  *(float2*)(outp + (size_t)node * F + lane * 2) = make_float2(t0, t1);
}

extern "C" void kernel_launch(void* const* d_in, const int* in_sizes, int n_in,
                              void* d_out, int out_size, void* d_ws, size_t ws_size,
                              hipStream_t stream) {
  const float* X  = (const float*)d_in[0];
  const int*   ei = (const int*)d_in[1];
  const float* W1 = (const float*)d_in[2];
  const float* b1 = (const float*)d_in[3];
  const float* W2 = (const float*)d_in[4];
  const float* b2 = (const float*)d_in[5];
  float* out = (float*)d_out;
  const int* src = ei;
  const int* dst = ei + N_EDGES;

  char* p = (char*)d_ws;
  unsigned short* h1h = (unsigned short*)p; p += (size_t)N_NODES * F_H1 * 2;
  unsigned short* h1l = (unsigned short*)p; p += (size_t)N_NODES * F_H1 * 2;
  unsigned short* h2h = (unsigned short*)p; p += (size_t)N_NODES * F_H2 * 2;
  unsigned short* h2l = (unsigned short*)p; p += (size_t)N_NODES * F_H2 * 2;
  unsigned short* Wt1h = (unsigned short*)p; p += (size_t)F_IN * F_H1 * 2;
  unsigned short* Wt1l = (unsigned short*)p; p += (size_t)F_IN * F_H1 * 2;
  unsigned short* Wt2h = (unsigned short*)p; p += (size_t)F_H1 * F_H2 * 2;
  unsigned short* Wt2l = (unsigned short*)p; p += (size_t)F_H1 * F_H2 * 2;
  float* dinv = (float*)p;                  p += 50048 * 4;
  int* counts = (int*)p;                    p += 50048 * 4;
  int* rowstart = (int*)p;                  p += 50056 * 4;
  int* cursor = (int*)p;                    p += 50048 * 4;
  int2* csr = (int2*)p;                     p += (size_t)N_EDGES * 8;

  // --- CSR + normalization + weight prep ---
  hipMemsetAsync(counts, 0, N_NODES * sizeof(int), stream);
  constexpr int PREP_IDS = F_IN * F_H1 + F_H1 * F_H2 + N_EDGES;
  k_prep<<<(PREP_IDS + 255) / 256, 256, 0, stream>>>(W1, Wt1h, Wt1l, W2, Wt2h,
                                                     Wt2l, dst, counts);
  k_scan<<<1, 1024, 0, stream>>>(counts, rowstart, cursor, dinv, N_NODES);
  k_fill<<<(N_EDGES + 255) / 256, 256, 0, stream>>>(src, dst, cursor, dinv, csr,
                                                    N_EDGES);

  // --- layer 1 GEMM: h1 = X @ W1 ---
  dim3 g1(F_H1 / 128, (N_NODES + 127) / 128);
  k_mm<true><<<g1, 512, 0, stream>>>(X, nullptr, Wt1h, Wt1l, h1h, h1l,
                                     N_NODES, F_H1, F_IN);

  // --- fused agg1 + epilogue + mm2: h2 = leaky(agg(h1)+b1) @ W2 ---
  k_aggmm<<<N_NODES / 16, 256, 0, stream>>>(h1h, h1l, rowstart, csr, dinv, b1,
                                            Wt2h, Wt2l, h2h, h2l, N_NODES);

  // --- layer 2 agg + epilogue -> out ---
  k_agg2<<<(N_NODES + 3) / 4, 256, 0, stream>>>(h2h, h2l, rowstart, csr, dinv,
                                                b2, out, N_NODES);
}

// Round 14
// 300.933 us; speedup vs baseline: 1.0946x; 1.0946x over previous
//
#include <hip/hip_runtime.h>

constexpr int N_NODES = 50000;
constexpr int N_EDGES = 800000;
constexpr int F_IN  = 512;
constexpr int F_H1  = 256;
constexpr int F_H2  = 128;

typedef short  short8  __attribute__((ext_vector_type(8)));
typedef float  f32x4   __attribute__((ext_vector_type(4)));
typedef unsigned short us4 __attribute__((ext_vector_type(4)));

__device__ __forceinline__ unsigned short bf16_rn(float f) {
  unsigned int u = __float_as_uint(f);
  return (unsigned short)((u + 0x7FFFu + ((u >> 16) & 1u)) >> 16);
}
__device__ __forceinline__ float bf16_tof(unsigned short h) {
  return __uint_as_float(((unsigned int)h) << 16);
}

// ---------------- prep: weight transpose+split AND degree count (one launch) -
__global__ __launch_bounds__(256) void k_prep(const float* __restrict__ W1,
                                              unsigned short* __restrict__ W1h,
                                              unsigned short* __restrict__ W1l,
                                              const float* __restrict__ W2,
                                              unsigned short* __restrict__ W2h,
                                              unsigned short* __restrict__ W2l,
                                              const int* __restrict__ dst,
                                              int* __restrict__ cnt) {
  constexpr int T1 = F_IN * F_H1;
  constexpr int T2 = F_H1 * F_H2;
  constexpr int TW = T1 + T2;
  int id = blockIdx.x * 256 + threadIdx.x;
  if (id < T1) {
    int n = id / F_IN, k = id - n * F_IN;
    float f = W1[(size_t)k * F_H1 + n];
    unsigned short h = bf16_rn(f);
    W1h[id] = h;
    W1l[id] = bf16_rn(f - bf16_tof(h));
  } else if (id < TW) {
    int id2 = id - T1;
    int n = id2 / F_H1, k = id2 - n * F_H1;
    float f = W2[(size_t)k * F_H2 + n];
    unsigned short h = bf16_rn(f);
    W2h[id2] = h;
    W2l[id2] = bf16_rn(f - bf16_tof(h));
  } else if (id - TW < N_EDGES) {
    atomicAdd(&cnt[dst[id - TW]], 1);
  }
}

// Single block, 1024 threads, 4 elems/thread, shuffle-based scan.
__global__ __launch_bounds__(1024) void k_scan(const int* __restrict__ cnt,
                                               int* __restrict__ rowstart,
                                               int* __restrict__ cursor,
                                               float* __restrict__ dinv, int n) {
  __shared__ int wsum[16];
  __shared__ int carry_s;
  const int t = threadIdx.x;
  const int wid = t >> 6, lane = t & 63;
  if (t == 0) { carry_s = 0; rowstart[0] = 0; }
  __syncthreads();
  for (int base = 0; base < n; base += 4096) {
    const int i0 = base + t * 4;
    int v[4];
    if (i0 + 4 <= n) {
      const int4 v4 = *(const int4*)&cnt[i0];
      v[0] = v4.x; v[1] = v4.y; v[2] = v4.z; v[3] = v4.w;
    } else {
#pragma unroll
      for (int j = 0; j < 4; ++j) v[j] = (i0 + j < n) ? cnt[i0 + j] : 0;
    }
#pragma unroll
    for (int j = 0; j < 4; ++j)
      if (i0 + j < n) dinv[i0 + j] = rsqrtf((float)v[j] + 1.0f);
    const int tsum = v[0] + v[1] + v[2] + v[3];
    int x = tsum;
#pragma unroll
    for (int off = 1; off < 64; off <<= 1) {
      int y = __shfl_up(x, off);
      if (lane >= off) x += y;
    }
    if (lane == 63) wsum[wid] = x;
    __syncthreads();
    if (wid == 0) {
      int s = (lane < 16) ? wsum[lane] : 0;
#pragma unroll
      for (int off = 1; off < 16; off <<= 1) {
        int y = __shfl_up(s, off);
        if (lane >= off) s += y;
      }
      if (lane < 16) wsum[lane] = s;
    }
    __syncthreads();
    const int carry = carry_s;
    const int woff = (wid == 0) ? 0 : wsum[wid - 1];
    int run = carry + woff + x - tsum;  // exclusive prefix of first elem
#pragma unroll
    for (int j = 0; j < 4; ++j) {
      if (i0 + j < n) {
        cursor[i0 + j] = run;
        run += v[j];
        rowstart[i0 + j + 1] = run;
      }
    }
    __syncthreads();
    if (t == 1023) carry_s = carry + woff + x;
    __syncthreads();
  }
}

// Fill packed CSR: (src, coef) with coef = dinv[src]*dinv[dst].
__global__ __launch_bounds__(256) void k_fill(const int* __restrict__ src,
                                              const int* __restrict__ dst,
                                              int* __restrict__ cursor,
                                              const float* __restrict__ dinv,
                                              int2* __restrict__ csr, int e) {
  int i = blockIdx.x * 256 + threadIdx.x;
  if (i < e) {
    const int s = src[i], d = dst[i];
    int slot = atomicAdd(&cursor[d], 1);
    csr[slot] = make_int2(s, __float_as_int(dinv[s] * dinv[d]));
  }
}

// ---------------- 2-term split-bf16 MFMA GEMM, BK=32, 24KB LDS ---------------
// C = A @ B, A ~ bf16-hi (1 plane), B = Bh+Bl pre-transposed Bt[N][K].
// C written as two bf16 planes. 128x128 tile, BK=32. LDS: 3 planes x
// 128 rows x 32 elems (64B rows), granule swizzle gs = g ^ ((r>>1)&3):
// ds_write (4 lanes/row, 64B contiguous) and b128 frag reads (8 distinct
// 16B slots per 128B) both conflict-free. 24KB/block -> 4 blocks/CU at
// VGPR<=64 (R12 measured 60 at BK=64; staging halves here). 512 threads =
// 8 waves (2x4), wave = 64x32 out via 4x2 frags. T14 depth-1 reg prefetch.
template <bool A_IS_F32>
__global__ __launch_bounds__(512, 2) void k_mm(const float* __restrict__ Af,
                                               const unsigned short* __restrict__ Ah,
                                               const unsigned short* __restrict__ Bth,
                                               const unsigned short* __restrict__ Btl,
                                               unsigned short* __restrict__ Chh,
                                               unsigned short* __restrict__ Cll,
                                               int M, int N, int K) {
  __shared__ unsigned short Ah_s[128 * 32];
  __shared__ unsigned short Bh_s[128 * 32];
  __shared__ unsigned short Bl_s[128 * 32];
  const int tid = threadIdx.x;
  const int wid = tid >> 6, lane = tid & 63;
  const int wm = wid >> 2, wn = wid & 3;
  const int lr = lane & 15, lg = lane >> 4;
  const int col0 = blockIdx.x * 128, row0 = blockIdx.y * 128;

  f32x4 acc[4][2] = {};

  // staging coords: thread t -> row r_s = t>>2 (0..127), granule g_s = t&3
  const int r_s = tid >> 2, g_s = tid & 3;
  const int doff = r_s * 32 + (g_s ^ ((r_s >> 1) & 3)) * 8;  // swizzled dest
  const bool a_ok = (row0 + r_s) < M;
  const size_t a_row = (size_t)(row0 + r_s) * K;
  const size_t b_row = (size_t)(col0 + r_s) * K;

  // depth-1 prefetch registers
  float4 af0, af1;
  short8 ahr, bhr, blr;

  auto load_tile = [&](int k0) {
    const int kk = k0 + g_s * 8;
    if (A_IS_F32) {
      af0 = make_float4(0.f, 0.f, 0.f, 0.f);
      af1 = af0;
      if (a_ok) {
        const float* ap = Af + a_row + kk;
        af0 = *(const float4*)ap;
        af1 = *(const float4*)(ap + 4);
      }
    } else {
      ahr = short8{};
      if (a_ok) ahr = *(const short8*)&Ah[a_row + kk];
    }
    bhr = *(const short8*)&Bth[b_row + kk];
    blr = *(const short8*)&Btl[b_row + kk];
  };

  auto store_tile = [&]() {
    if (A_IS_F32) {
      const float fv[8] = {af0.x, af0.y, af0.z, af0.w, af1.x, af1.y, af1.z, af1.w};
      short8 hv;
#pragma unroll
      for (int j = 0; j < 8; ++j) hv[j] = (short)bf16_rn(fv[j]);
      *(short8*)&Ah_s[doff] = hv;
    } else {
      *(short8*)&Ah_s[doff] = ahr;
    }
    *(short8*)&Bh_s[doff] = bhr;
    *(short8*)&Bl_s[doff] = blr;
  };

  const int nsteps = K >> 5;
  load_tile(0);
  for (int s = 0; s < nsteps; ++s) {
    store_tile();
    __syncthreads();
    if (s + 1 < nsteps) load_tile((s + 1) << 5);  // prefetch next tile
    // ---- compute tile s: D += Ah*Bh + Ah*Bl ----
    short8 ah[4], bh[2], bl[2];
#pragma unroll
    for (int m = 0; m < 4; ++m) {
      const int r = wm * 64 + m * 16 + lr;
      ah[m] = *(const short8*)&Ah_s[r * 32 + (lg ^ ((r >> 1) & 3)) * 8];
    }
#pragma unroll
    for (int n = 0; n < 2; ++n) {
      const int r = wn * 32 + n * 16 + lr;
      const int off = r * 32 + (lg ^ ((r >> 1) & 3)) * 8;
      bh[n] = *(const short8*)&Bh_s[off];
      bl[n] = *(const short8*)&Bl_s[off];
    }
#pragma unroll
    for (int m = 0; m < 4; ++m)
#pragma unroll
      for (int n = 0; n < 2; ++n)
        acc[m][n] = __builtin_amdgcn_mfma_f32_16x16x32_bf16(ah[m], bh[n],
                                                            acc[m][n], 0, 0, 0);
#pragma unroll
    for (int m = 0; m < 4; ++m)
#pragma unroll
      for (int n = 0; n < 2; ++n)
        acc[m][n] = __builtin_amdgcn_mfma_f32_16x16x32_bf16(ah[m], bl[n],
                                                            acc[m][n], 0, 0, 0);
    __syncthreads();
  }
  // ---- store C as bf16 hi/lo planes ----
#pragma unroll
  for (int m = 0; m < 4; ++m) {
#pragma unroll
    for (int j = 0; j < 4; ++j) {
      const int row = row0 + wm * 64 + m * 16 + (lane >> 4) * 4 + j;
      if (row < M) {
        const size_t base = (size_t)row * N + col0 + wn * 32 + lr;
#pragma unroll
        for (int n = 0; n < 2; ++n) {
          const float v = acc[m][n][j];
          const unsigned short hv = bf16_rn(v);
          Chh[base + n * 16] = hv;
          Cll[base + n * 16] = bf16_rn(v - bf16_tof(hv));
        }
      }
    }
  }
}

// ---------------- gather aggregation + fused epilogue ----------------
// One wave per node; 4-wide edge unroll. Neighbors gathered from hi plane;
// self-loop term reconstructed from hi+lo (exact to 2^-17).
// out = leaky_relu(sum_in coef*h[src] + dinv^2*h[node] + bias)
// SPLIT_OUT: write bf16 hi only (next GEMM uses 2-term split, no A-lo).
template <int F, bool SPLIT_OUT>
__global__ __launch_bounds__(256) void k_agg(const unsigned short* __restrict__ hh,
                                             const unsigned short* __restrict__ hl,
                                             const int* __restrict__ rowstart,
                                             const int2* __restrict__ csr,
                                             const float* __restrict__ dinv,
                                             const float* __restrict__ bias,
                                             float* __restrict__ outp,
                                             unsigned short* __restrict__ outh,
                                             int n) {
  constexpr int V = F / 64;
  const int node = (blockIdx.x * 256 + threadIdx.x) >> 6;
  const int lane = threadIdx.x & 63;
  if (node >= n) return;
  const float dn = dinv[node];
  const int e0 = rowstart[node];
  const int cnt = rowstart[node + 1] - e0;
  const int2* cp = csr + e0;
  float acc[V] = {};
  int i = 0;

  auto gather = [&](int s, float f[V]) {
    if constexpr (V == 4) {
      const uint2 u = *(const uint2*)(hh + (size_t)s * F + lane * 4);
      f[0] = __uint_as_float(u.x << 16);
      f[1] = __uint_as_float(u.x & 0xffff0000u);
      f[2] = __uint_as_float(u.y << 16);
      f[3] = __uint_as_float(u.y & 0xffff0000u);
    } else {
      const unsigned int u = *(const unsigned int*)(hh + (size_t)s * F + lane * 2);
      f[0] = __uint_as_float(u << 16);
      f[1] = __uint_as_float(u & 0xffff0000u);
    }
  };

  for (; i + 4 <= cnt; i += 4) {
    const int2 p0 = cp[i], p1 = cp[i + 1], p2 = cp[i + 2], p3 = cp[i + 3];
    float f0[V], f1[V], f2[V], f3[V];
    gather(p0.x, f0);
    gather(p1.x, f1);
    gather(p2.x, f2);
    gather(p3.x, f3);
    const float c0 = __int_as_float(p0.y), c1 = __int_as_float(p1.y);
    const float c2 = __int_as_float(p2.y), c3 = __int_as_float(p3.y);
#pragma unroll
    for (int j = 0; j < V; ++j)
      acc[j] += c0 * f0[j] + c1 * f1[j] + c2 * f2[j] + c3 * f3[j];
  }
  for (; i < cnt; ++i) {
    const int2 p = cp[i];
    const float c = __int_as_float(p.y);
    float f[V];
    gather(p.x, f);
#pragma unroll
    for (int j = 0; j < V; ++j) acc[j] += c * f[j];
  }

  const float sc = dn * dn;
  const unsigned short* shp = hh + (size_t)node * F + lane * V;
  const unsigned short* slp = hl + (size_t)node * F + lane * V;
  const float* bp = bias + lane * V;
  float r[V];
#pragma unroll
  for (int j = 0; j < V; ++j) {
    const float hself = bf16_tof(shp[j]) + bf16_tof(slp[j]);
    float t = acc[j] + sc * hself + bp[j];
    r[j] = fmaxf(t, 0.2f * t);
  }
  if constexpr (SPLIT_OUT) {
    unsigned short hv[V];
#pragma unroll
    for (int j = 0; j < V; ++j) hv[j] = bf16_rn(r[j]);
    if constexpr (V == 4) {
      *(us4*)&outh[(size_t)node * F + lane * 4] = us4{hv[0], hv[1], hv[2], hv[3]};
    } else {
#pragma unroll
      for (int j = 0; j < V; ++j) outh[(size_t)node * F + lane * V + j] = hv[j];
    }
  } else {
    float* op = outp + (size_t)node * F + lane * V;
    if constexpr (V == 4) {
      *(float4*)op = make_float4(r[0], r[1], r[2], r[3]);
    } else {
      *(float2*)op = make_float2(r[0], r[1]);
    }
  }
}

extern "C" void kernel_launch(void* const* d_in, const int* in_sizes, int n_in,
                              void* d_out, int out_size, void* d_ws, size_t ws_size,
                              hipStream_t stream) {
  const float* X  = (const float*)d_in[0];
  const int*   ei = (const int*)d_in[1];
  const float* W1 = (const float*)d_in[2];
  const float* b1 = (const float*)d_in[3];
  const float* W2 = (const float*)d_in[4];
  const float* b2 = (const float*)d_in[5];
  float* out = (float*)d_out;
  const int* src = ei;
  const int* dst = ei + N_EDGES;

  char* p = (char*)d_ws;
  unsigned short* h1h = (unsigned short*)p; p += (size_t)N_NODES * F_H1 * 2;
  unsigned short* h1l = (unsigned short*)p; p += (size_t)N_NODES * F_H1 * 2;
  unsigned short* z1h = (unsigned short*)p; p += (size_t)N_NODES * F_H1 * 2;
  unsigned short* Wt1h = (unsigned short*)p; p += (size_t)F_IN * F_H1 * 2;
  unsigned short* Wt1l = (unsigned short*)p; p += (size_t)F_IN * F_H1 * 2;
  unsigned short* Wt2h = (unsigned short*)p; p += (size_t)F_H1 * F_H2 * 2;
  unsigned short* Wt2l = (unsigned short*)p; p += (size_t)F_H1 * F_H2 * 2;
  float* dinv = (float*)p;                  p += 50048 * 4;
  int* counts = (int*)p;                    p += 50048 * 4;
  int* rowstart = (int*)p;                  p += 50056 * 4;
  int* cursor = (int*)p;                    p += 50048 * 4;
  int2* csr = (int2*)p;                     p += (size_t)N_EDGES * 8;
  unsigned short* h2h = h1h;  // h1 planes dead after agg1
  unsigned short* h2l = h1l;

  // --- CSR + normalization + weight prep ---
  hipMemsetAsync(counts, 0, N_NODES * sizeof(int), stream);
  constexpr int PREP_IDS = F_IN * F_H1 + F_H1 * F_H2 + N_EDGES;
  k_prep<<<(PREP_IDS + 255) / 256, 256, 0, stream>>>(W1, Wt1h, Wt1l, W2, Wt2h,
                                                     Wt2l, dst, counts);
  k_scan<<<1, 1024, 0, stream>>>(counts, rowstart, cursor, dinv, N_NODES);
  k_fill<<<(N_EDGES + 255) / 256, 256, 0, stream>>>(src, dst, cursor, dinv, csr,
                                                    N_EDGES);

  // --- layer 1: h1 = X @ W1 ---
  dim3 g1(F_H1 / 128, (N_NODES + 127) / 128);
  k_mm<true><<<g1, 512, 0, stream>>>(X, nullptr, Wt1h, Wt1l, h1h, h1l,
                                     N_NODES, F_H1, F_IN);
  k_agg<F_H1, true><<<(N_NODES + 3) / 4, 256, 0, stream>>>(
      h1h, h1l, rowstart, csr, dinv, b1, nullptr, z1h, N_NODES);

  // --- layer 2: h2 = z1 @ W2 ---
  dim3 g2(F_H2 / 128, (N_NODES + 127) / 128);
  k_mm<false><<<g2, 512, 0, stream>>>(nullptr, z1h, Wt2h, Wt2l, h2h, h2l,
                                      N_NODES, F_H2, F_H1);
  k_agg<F_H2, false><<<(N_NODES + 3) / 4, 256, 0, stream>>>(
      h2h, h2l, rowstart, csr, dinv, b2, out, nullptr, N_NODES);
}